// Round 6
// baseline (503.232 us; speedup 1.0000x reference)
//
#include <hip/hip_runtime.h>
#include <math.h>

// ---------------------------------------------------------------------------
// Round 11: global_load_lds staging (async DMA, no VGPR round-trip).
// The compiler keeps squeezing staged values out of registers (VGPR=60 on
// c1p1 despite launch_bounds); register-routed staging is the bloat. Replace
// it with __builtin_amdgcn_global_load_lds:
//  - c1p1 interior blocks: 4 DMA/row, wave-partitioned rows (edge blocks keep
//    the old clamped path).
//  - c2p2 interior: 2 DMA/row; the g=123 right-pad zero moves to registers
//    (if ow==61: rr[c][2]=0) since DMA overwrites col 124.
//  - fc1: DMA with pre-swizzled global source column (kl ^ ((m&7)<<2)) so the
//    linear LDS + swizzled read recovers exactly A[m][ch*64+k] (rule: source
//    permutation == read permutation). Tail chunk 872 keeps the register path.
// No arithmetic reordering -> bit-identical outputs.
// ---------------------------------------------------------------------------

__device__ __forceinline__ void gload_lds4(const float* g, float* l) {
    __builtin_amdgcn_global_load_lds(
        (const __attribute__((address_space(1))) unsigned int*)g,
        (__attribute__((address_space(3))) unsigned int*)l, 4, 0, 0);
}

// conv1+pool1. Block: image b (blockIdx.y), 8 pooled rows (t=blockIdx.x).
// 4 waves = 2 col-spans x 2 row-strips. lane -> conv col ow = 62*span + lane.
// LDS: xs[r][c] holds input col g=c-1 (col 0 = left pad); row 21 + cols
// 251..257 are write-only garbage sinks.
__global__ __launch_bounds__(256, 3) void k_c1p1(const float* __restrict__ x,
                                                 const float* __restrict__ w,
                                                 const float* __restrict__ bias,
                                                 float* __restrict__ p1) {
    __shared__ float xs[22][258];

    const int t    = blockIdx.x;          // 0..15
    const int b    = blockIdx.y;          // 0..255
    const int tid  = threadIdx.x;
    const int lane = tid & 63;
    const int wv   = tid >> 6;
    const int s    = wv & 1;              // col span
    const int q    = wv >> 1;             // row strip
    const int ow   = 62 * s + lane;
    const int owc  = min(ow, 123);
    const int owc2 = 2 * owc;
    const int ihlo = 16 * t - 1;

    const int sr  = __builtin_amdgcn_readfirstlane(tid >> 7); // wave-uniform
    const int sm  = tid & 127;            // float2 index
    const int smc = min(sm, 124);

    float acc[5][6];
#pragma unroll
    for (int j = 0; j < 5; ++j)
#pragma unroll
        for (int oc = 0; oc < 6; ++oc) acc[j][oc] = 0.f;

    const float* xb = x + (size_t)b * 3 * 62500;
    const bool interior = (t >= 1) && (t <= 14);   // all 21 rows in-bounds

    if (tid < 21) xs[tid][0] = 0.f;       // col -1 pad (never overwritten)

#pragma unroll 1
    for (int ci = 0; ci < 3; ++ci) {
        __syncthreads();                  // prior reads done; pad visible
        const float* xc = xb + (size_t)ci * 62500;
        if (interior) {
            // async DMA: wave wv stages rows r = wv, wv+4, ...  4 instrs/row
            // (k=3 spills cols 250..255 -> reads next input row, in-bounds
            //  for interior t; lands in sink cols 251..257, never read)
            for (int r = wv; r < 21; r += 4) {
                const float* src = xc + (size_t)(ihlo + r) * 250 + lane;
#pragma unroll
                for (int k = 0; k < 4; ++k)
                    gload_lds4(src + 64 * k, &xs[r][1 + 64 * k]);
            }
        } else {
            float2 vv[11];
#pragma unroll
            for (int i = 0; i < 11; ++i) {
                int r   = 2 * i + sr;                 // scalar
                int ih  = ihlo + r;                   // scalar
                int ihc = min(max(ih, 0), 249);       // scalar clamp
                bool ok = (ih >= 0) && (ih < 250);    // scalar
                float2 raw = *(const float2*)(xc + (size_t)ihc * 250 + (smc << 1));
                vv[i].x = ok ? raw.x : 0.f;
                vv[i].y = ok ? raw.y : 0.f;
            }
#pragma unroll
            for (int i = 0; i < 11; ++i) {
                int r = 2 * i + sr;                   // r=21 -> sink row
                xs[r][2 * sm + 1] = vv[i].x;          // global col 2sm
                xs[r][2 * sm + 2] = vv[i].y;          // global col 2sm+1
            }
        }
        __syncthreads();                  // drains DMA (vmcnt) + ds writes

        // load all 13 distinct rows once (compile-time indices -> registers)
        float rr[13][5];
#pragma unroll
        for (int r = 0; r < 13; ++r) {
            const float* pp = &xs[8 * q + r][owc2];
            rr[r][0] = pp[0]; rr[r][1] = pp[1]; rr[r][2] = pp[2];
            rr[r][3] = pp[3]; rr[r][4] = pp[4];
        }
#pragma unroll
        for (int kh = 0; kh < 5; ++kh) {
            float wk[6][5];
#pragma unroll
            for (int oc = 0; oc < 6; ++oc)
#pragma unroll
                for (int kw = 0; kw < 5; ++kw)
                    wk[oc][kw] = w[((oc * 3 + ci) * 5 + kh) * 5 + kw];
#pragma unroll
            for (int j = 0; j < 5; ++j) {
                const float* rp = rr[2 * j + kh];   // compile-time index
#pragma unroll
                for (int oc = 0; oc < 6; ++oc) {
                    float a = acc[j][oc];
                    a = fmaf(rp[0], wk[oc][0], a);
                    a = fmaf(rp[1], wk[oc][1], a);
                    a = fmaf(rp[2], wk[oc][2], a);
                    a = fmaf(rp[3], wk[oc][3], a);
                    a = fmaf(rp[4], wk[oc][4], a);
                    acc[j][oc] = a;
                }
            }
        }
    }

    // epilogue: bias+relu, vertical max, horizontal max via shuffle, store
    const int pw   = ow;
    const int oh0  = 8 * t + 4 * q;
    const bool cok = (lane < 63) && (pw < 123);
#pragma unroll
    for (int oc = 0; oc < 6; ++oc) {
        float bv = bias[oc];
        float r0 = fmaxf(acc[0][oc] + bv, 0.f);
        float r1 = fmaxf(acc[1][oc] + bv, 0.f);
        float r2 = fmaxf(acc[2][oc] + bv, 0.f);
        float r3 = fmaxf(acc[3][oc] + bv, 0.f);
        float r4 = fmaxf(acc[4][oc] + bv, 0.f);
        float vm0 = fmaxf(r0, r1), vm1 = fmaxf(r1, r2);
        float vm2 = fmaxf(r2, r3), vm3 = fmaxf(r3, r4);
        float p0 = fmaxf(vm0, __shfl_down(vm0, 1));
        float p1v = fmaxf(vm1, __shfl_down(vm1, 1));
        float p2v = fmaxf(vm2, __shfl_down(vm2, 1));
        float p3 = fmaxf(vm3, __shfl_down(vm3, 1));
        if (cok) {
            float* op = p1 + (((size_t)b * 6 + oc) * 123) * 123 + pw;
            if (oh0 + 0 < 123) op[(size_t)(oh0 + 0) * 123] = p0;
            if (oh0 + 1 < 123) op[(size_t)(oh0 + 1) * 123] = p1v;
            if (oh0 + 2 < 123) op[(size_t)(oh0 + 2) * 123] = p2v;
            if (oh0 + 3 < 123) op[(size_t)(oh0 + 3) * 123] = p3;
        }
    }
}

// conv2+pool2. Block: image b, 8 pooled rows (v=blockIdx.x).
// 4 waves = 4 row strips; lane = conv col. LDS rows 0..18 data, row 19 sink;
// col 0 left pad. Interior blocks stage via DMA (col 124 becomes garbage;
// the g=123 zero-pad is applied in registers: ow==61 -> rr[c][2]=0).
__global__ __launch_bounds__(256, 3) void k_c2p2(const float* __restrict__ p1,
                                                 const float* __restrict__ w,
                                                 const float* __restrict__ bias,
                                                 float* __restrict__ p2) {
    __shared__ float xs[20][130];

    const int v    = blockIdx.x;          // 0..7
    const int b    = blockIdx.y;
    const int tid  = threadIdx.x;
    const int lane = tid & 63;
    const int q    = tid >> 6;            // 0..3 (also the wave id)
    const int ow   = lane;
    const int owc  = min(ow, 61);
    const int owc2 = 2 * owc;
    const int ihlo = 16 * v - 1;

    const int sr   = __builtin_amdgcn_readfirstlane(tid >> 7); // wave-uniform
    const int sc   = tid & 127;           // 0..127
    const int scc  = min(sc, 122);
    const int wcol = (sc < 123) ? (sc + 1) : 129;   // sink col for edge lanes

    float acc[3][15];
#pragma unroll
    for (int j = 0; j < 3; ++j)
#pragma unroll
        for (int oc = 0; oc < 15; ++oc) acc[j][oc] = 0.f;

    const float* ib = p1 + (size_t)b * 6 * 15129;
    const bool interior = (v >= 1) && (v <= 6);   // all 19 rows in-bounds

    if (tid < 19) { xs[tid][0] = 0.f; xs[tid][124] = 0.f; }

#pragma unroll 1
    for (int ci = 0; ci < 6; ++ci) {
        __syncthreads();
        const float* xc = ib + (size_t)ci * 15129;
        if (interior) {
            // 2 DMA/row; k=1 covers cols 65..128 (src spill into next input
            // row is in-bounds for interior v; col 124 gets garbage -> the
            // zero-pad is applied in registers below)
            for (int r = q; r < 19; r += 4) {
                const float* src = xc + (size_t)(ihlo + r) * 123 + lane;
                gload_lds4(src,      &xs[r][1]);
                gload_lds4(src + 64, &xs[r][65]);
            }
        } else {
            float vv[10];
#pragma unroll
            for (int i = 0; i < 10; ++i) {
                int r   = 2 * i + sr;                 // scalar
                int ih  = ihlo + r;                   // scalar
                int ihc = min(max(ih, 0), 122);       // scalar clamp
                bool ok = (ih >= 0) && (ih < 123);    // scalar
                float raw = xc[(size_t)ihc * 123 + scc];
                vv[i] = ok ? raw : 0.f;
            }
#pragma unroll
            for (int i = 0; i < 10; ++i) {
                int r = 2 * i + sr;                   // r=19 -> sink row
                xs[r][wcol] = vv[i];
            }
            if (tid < 19) xs[tid][124] = 0.f;         // keep right pad zero
        }
        __syncthreads();

        // load all 7 distinct rows once: rows 4q + c, c=0..6
        float rr[7][3];
#pragma unroll
        for (int c = 0; c < 7; ++c) {
            const float* pp = &xs[4 * q + c][owc2];
            rr[c][0] = pp[0]; rr[c][1] = pp[1]; rr[c][2] = pp[2];
            if (ow == 61) rr[c][2] = 0.f;   // g=123 zero pad (reg-side)
        }
#pragma unroll
        for (int kh = 0; kh < 3; ++kh) {
            float wk[15][3];
#pragma unroll
            for (int oc = 0; oc < 15; ++oc)
#pragma unroll
                for (int kw = 0; kw < 3; ++kw)
                    wk[oc][kw] = w[((oc * 6 + ci) * 3 + kh) * 3 + kw];
#pragma unroll
            for (int j = 0; j < 3; ++j) {
                const float* rp = rr[2 * j + kh];
#pragma unroll
                for (int oc = 0; oc < 15; ++oc) {
                    float a = acc[j][oc];
                    a = fmaf(rp[0], wk[oc][0], a);
                    a = fmaf(rp[1], wk[oc][1], a);
                    a = fmaf(rp[2], wk[oc][2], a);
                    acc[j][oc] = a;
                }
            }
        }
    }

    const int pw   = ow;
    const int oh0  = 8 * v + 2 * q;
    const bool cok = (lane < 61);
#pragma unroll
    for (int oc = 0; oc < 15; ++oc) {
        float bv = bias[oc];
        float r0 = fmaxf(acc[0][oc] + bv, 0.f);
        float r1 = fmaxf(acc[1][oc] + bv, 0.f);
        float r2 = fmaxf(acc[2][oc] + bv, 0.f);
        float vm0 = fmaxf(r0, r1), vm1 = fmaxf(r1, r2);
        float p0 = fmaxf(vm0, __shfl_down(vm0, 1));
        float p1v = fmaxf(vm1, __shfl_down(vm1, 1));
        if (cok) {
            float* op = p2 + (((size_t)b * 15 + oc) * 61) * 61 + pw;
            if (oh0 + 0 < 61) op[(size_t)(oh0 + 0) * 61] = p0;
            if (oh0 + 1 < 61) op[(size_t)(oh0 + 1) * 61] = p1v;
        }
    }
}

// fc1 split-K GEMM: A=p2[256][55815], B=fc1_w[120][55815].
// grid (256 kb, 2 mt), BK=64. XOR-swizzled LDS; staging via global_load_lds
// with pre-swizzled global source column (source perm == read perm), so the
// k4 read loop is unchanged and recovers A[m][ch*64+k] exactly. Tail chunk
// 872 (partial, OOB risk for DMA) keeps the register-staged path.
__global__ __launch_bounds__(256) void k_fc1(const float* __restrict__ A,
                                             const float* __restrict__ B,
                                             float* __restrict__ partial) {
    __shared__ float As[128][64];
    __shared__ float Bs[128][64];
    const int K = 55815;
    int tid = threadIdx.x;
    int kb  = blockIdx.x;          // 0..255
    int m0  = blockIdx.y * 128;
    int mx  = tid >> 4;            // 0..15
    int nx  = tid & 15;            // 0..15
    int kl  = tid & 63;            // staging col (= lane)
    int wv  = tid >> 6;            // wave id
    int mb  = tid >> 6;            // staging row base (tail path)

    // zero-fill B rows 120..127 (whole rows -> swizzle-invariant)
    Bs[120 + mb][kl] = 0.f;
    Bs[124 + mb][kl] = 0.f;

    float acc[8][8];
#pragma unroll
    for (int i = 0; i < 8; ++i)
#pragma unroll
        for (int j = 0; j < 8; ++j) acc[i][j] = 0.f;

    for (int ch = kb; ch < 873; ch += 256) {   // 873 = ceil(55815/64)
        __syncthreads();                        // prev compute done
        if (ch != 872) {
            // DMA staging: wave wv stages rows m = wv, wv+4, ...
            // source col = kl ^ ((m&7)<<2)  (pre-swizzle; LDS dest linear)
            const float* Ab = A + (size_t)m0 * K + (size_t)ch * 64;
            const float* Bb = B + (size_t)ch * 64;
            for (int m = wv; m < 128; m += 4) {
                int kcol = kl ^ ((m & 7) << 2);
                gload_lds4(Ab + (size_t)m * K + kcol, &As[m][0]);
            }
            for (int m = wv; m < 120; m += 4) {
                int kcol = kl ^ ((m & 7) << 2);
                gload_lds4(Bb + (size_t)m * K + kcol, &Bs[m][0]);
            }
        } else {
            int k    = ch * 64 + kl;
            bool kok = (k < K);
            int kc   = kok ? k : K - 1;
#pragma unroll
            for (int batch = 0; batch < 4; ++batch) {
                float va[8], vb[8];
#pragma unroll
                for (int u = 0; u < 8; ++u) {
                    int m = mb + 4 * (batch * 8 + u);
                    va[u] = A[(size_t)(m0 + m) * K + kc];
                }
#pragma unroll
                for (int u = 0; u < 8; ++u) {
                    if (batch < 3 || u < 6) {      // B rows 0..119 only
                        int m = mb + 4 * (batch * 8 + u);
                        vb[u] = B[(size_t)m * K + kc];
                    }
                }
#pragma unroll
                for (int u = 0; u < 8; ++u) {
                    int m = mb + 4 * (batch * 8 + u);
                    As[m][kl ^ ((m & 7) << 2)] = kok ? va[u] : 0.f;
                }
#pragma unroll
                for (int u = 0; u < 8; ++u) {
                    if (batch < 3 || u < 6) {
                        int m = mb + 4 * (batch * 8 + u);
                        Bs[m][kl ^ ((m & 7) << 2)] = kok ? vb[u] : 0.f;
                    }
                }
            }
        }
        __syncthreads();                        // vmcnt drained, tile visible
#pragma unroll 2
        for (int k4 = 0; k4 < 16; ++k4) {
            float4 af[8], bf[8];
#pragma unroll
            for (int i = 0; i < 8; ++i) {
                int m = mx + 16 * i;
                af[i] = *(const float4*)&As[m][(k4 * 4) ^ ((m & 7) << 2)];
            }
#pragma unroll
            for (int j = 0; j < 8; ++j) {
                int n = nx + 16 * j;
                bf[j] = *(const float4*)&Bs[n][(k4 * 4) ^ ((n & 7) << 2)];
            }
#pragma unroll
            for (int i = 0; i < 8; ++i)
#pragma unroll
                for (int j = 0; j < 8; ++j) {
                    acc[i][j] = fmaf(af[i].x, bf[j].x, acc[i][j]);
                    acc[i][j] = fmaf(af[i].y, bf[j].y, acc[i][j]);
                    acc[i][j] = fmaf(af[i].z, bf[j].z, acc[i][j]);
                    acc[i][j] = fmaf(af[i].w, bf[j].w, acc[i][j]);
                }
        }
    }

    float* pp = partial + (size_t)kb * 30720;
#pragma unroll
    for (int i = 0; i < 8; ++i) {
        int m = m0 + mx + 16 * i;
#pragma unroll
        for (int j = 0; j < 8; ++j) {
            int n = nx + 16 * j;
            if (n < 120) pp[m * 120 + n] = acc[i][j];
        }
    }
}

// reduce stage 1: block (g, s) sums partials kb = 32s..32s+31 for its 256 idx
__global__ __launch_bounds__(256) void k_fc1red1(const float* __restrict__ partial,
                                                 float* __restrict__ partial2) {
    int idx = blockIdx.x * 256 + threadIdx.x;   // 0..30719
    int s   = blockIdx.y;                       // 0..7
    const float* p = partial + (size_t)(s * 32) * 30720 + idx;
    float acc = 0.f;
#pragma unroll 8
    for (int kb = 0; kb < 32; ++kb) acc += p[(size_t)kb * 30720];
    partial2[(size_t)s * 30720 + idx] = acc;
}

// reduce stage 2: 8-way + bias + relu -> fc1out[256][120]
__global__ __launch_bounds__(256) void k_fc1red2(const float* __restrict__ partial2,
                                                 const float* __restrict__ bias,
                                                 float* __restrict__ out) {
    int idx = blockIdx.x * 256 + threadIdx.x;   // 30720
    int n = idx % 120;
    float s = bias[n];
#pragma unroll
    for (int k = 0; k < 8; ++k) s += partial2[(size_t)k * 30720 + idx];
    out[idx] = fmaxf(s, 0.f);
}

// fc2: features[256][84] = fc1out[256][120] @ w[84][120]^T + b
__global__ __launch_bounds__(256) void k_fc2(const float* __restrict__ h,
                                             const float* __restrict__ w,
                                             const float* __restrict__ bias,
                                             float* __restrict__ out) {
    int idx = blockIdx.x * 256 + threadIdx.x;   // 21504
    int n = idx % 84;
    int m = idx / 84;
    const float* hp = h + m * 120;
    const float* wp = w + n * 120;
    float s = bias[n];
#pragma unroll 4
    for (int k = 0; k < 120; ++k) s = fmaf(hp[k], wp[k], s);
    out[idx] = s;
}

// head: fc3 -> tanh-param layer -> sigmoid; also row norms of features
__global__ __launch_bounds__(256) void k_head(const float* __restrict__ f,
                                              const float* __restrict__ w3,
                                              const float* __restrict__ b3,
                                              const float* __restrict__ plw,
                                              const float* __restrict__ plb,
                                              const float* __restrict__ pls,
                                              const float* __restrict__ plbias,
                                              float* __restrict__ probs,
                                              float* __restrict__ norms) {
    int b = threadIdx.x;            // 0..255, single block
    const float* fp = f + b * 84;
    float nsq = 0.f, lg = b3[0];
#pragma unroll 4
    for (int k = 0; k < 84; ++k) {
        float v = fp[k];
        nsq = fmaf(v, v, nsq);
        lg  = fmaf(v, w3[k], lg);
    }
    float z = tanhf(lg * plw[0] + plb[0]) * pls[0] + plbias[0];
    probs[b] = 1.f / (1.f + expf(-z));
    norms[b] = sqrtf(nsq);
}

// graph: block i computes cosine-sim row i, adjacency, degree-weighted agg
__global__ __launch_bounds__(256) void k_graph(const float* __restrict__ f,
                                               const float* __restrict__ probs,
                                               const float* __restrict__ norms,
                                               float* __restrict__ out) {
    __shared__ float fi[84];
    __shared__ float sd[4], sv[4];
    int i = blockIdx.x;
    int j = threadIdx.x;
    if (j < 84) fi[j] = f[i * 84 + j];
    __syncthreads();
    const float* fj = f + j * 84;
    float dot = 0.f;
#pragma unroll 4
    for (int k = 0; k < 84; ++k) dot = fmaf(fi[k], fj[k], dot);
    float sim = dot / (norms[i] * norms[j] + 1e-12f);
    bool adj = (j != i) && (sim >= 0.0f);
    float d = adj ? 1.f : 0.f;
    float v = adj ? probs[j] : 0.f;
#pragma unroll
    for (int off = 32; off >= 1; off >>= 1) {
        d += __shfl_down(d, off);
        v += __shfl_down(v, off);
    }
    int wave = j >> 6, lane = j & 63;
    if (lane == 0) { sd[wave] = d; sv[wave] = v; }
    __syncthreads();
    if (j == 0) {
        float D = sd[0] + sd[1] + sd[2] + sd[3];
        float V = sv[0] + sv[1] + sv[2] + sv[3];
        float nm = (D > 0.f) ? (V / fmaxf(D, 1.f)) : 0.f;
        float agg = (probs[i] + nm) / (1.f + D);
        out[2 * i]     = agg;
        out[2 * i + 1] = 1.f - agg;
    }
}

extern "C" void kernel_launch(void* const* d_in, const int* in_sizes, int n_in,
                              void* d_out, int out_size, void* d_ws, size_t ws_size,
                              hipStream_t stream) {
    const float* x    = (const float*)d_in[0];
    const float* w1   = (const float*)d_in[1];
    const float* b1   = (const float*)d_in[2];
    const float* w2   = (const float*)d_in[3];
    const float* b2   = (const float*)d_in[4];
    const float* fw1  = (const float*)d_in[5];
    const float* fb1  = (const float*)d_in[6];
    const float* fw2  = (const float*)d_in[7];
    const float* fb2  = (const float*)d_in[8];
    const float* fw3  = (const float*)d_in[9];
    const float* fb3  = (const float*)d_in[10];
    const float* plw  = (const float*)d_in[11];
    const float* plb  = (const float*)d_in[12];
    const float* pls  = (const float*)d_in[13];
    const float* plbi = (const float*)d_in[14];
    float* out = (float*)d_out;

    float* ws = (float*)d_ws;
    float* p1       = ws;                          // 23,238,144 f
    float* p2       = p1 + 23238144;               // 14,288,640 f
    float* partial  = p2 + 14288640;               // 7,864,320 f
    float* fc1out   = partial + 7864320;           // 30,720 f
    float* features = fc1out + 30720;              // 21,504 f
    float* probs    = features + 21504;            // 256 f
    float* norms    = probs + 256;                 // 256 f
    float* partial2 = norms + 256;                 // 245,760 f

    k_c1p1<<<dim3(16, 256), 256, 0, stream>>>(x, w1, b1, p1);
    k_c2p2<<<dim3(8, 256), 256, 0, stream>>>(p1, w2, b2, p2);
    k_fc1<<<dim3(256, 2), 256, 0, stream>>>(p2, fw1, partial);
    k_fc1red1<<<dim3(120, 8), 256, 0, stream>>>(partial, partial2);
    k_fc1red2<<<120, 256, 0, stream>>>(partial2, fb1, fc1out);
    k_fc2<<<84, 256, 0, stream>>>(fc1out, fw2, fb2, features);
    k_head<<<1, 256, 0, stream>>>(features, fw3, fb3, plw, plb, pls, plbi,
                                  probs, norms);
    k_graph<<<256, 256, 0, stream>>>(features, probs, norms, out);
}

// Round 7
// 477.878 us; speedup vs baseline: 1.0531x; 1.0531x over previous
//
#include <hip/hip_runtime.h>
#include <math.h>

// ---------------------------------------------------------------------------
// Round 12: DMA + double-buffered LDS pipeline for the convs (one barrier per
// ci). Round-11 kept DMA serial (issue -> drain -> compute) and was neutral;
// the win is asynchrony: issue DMA(ci+1) AFTER this iteration's ds_reads,
// overlap it with the FMA block, drain at the next iteration's barrier.
// DMA staging holds nothing in VGPRs, so the double-buffer does not recreate
// round-9's register squeeze. Edge blocks keep the serial clamped path.
// k_fc1 reverted to the round-10 register-staged version (best-known 483us
// state); round-11's fc1 DMA was part of a +20us regression.
// ---------------------------------------------------------------------------

__device__ __forceinline__ void gload_lds4(const float* g, float* l) {
    __builtin_amdgcn_global_load_lds(
        (const __attribute__((address_space(1))) unsigned int*)g,
        (__attribute__((address_space(3))) unsigned int*)l, 4, 0, 0);
}

// conv1+pool1. Block: image b (blockIdx.y), 8 pooled rows (t=blockIdx.x).
// 4 waves = 2 col-spans x 2 row-strips. lane -> conv col ow = 62*span + lane.
// LDS: xs[buf][r][c] holds input col g=c-1 (col 0 = left pad); row 21 and
// cols 251..257 are write-only garbage sinks.
__global__ __launch_bounds__(256, 3) void k_c1p1(const float* __restrict__ x,
                                                 const float* __restrict__ w,
                                                 const float* __restrict__ bias,
                                                 float* __restrict__ p1) {
    __shared__ float xs[2][22][258];

    const int t    = blockIdx.x;          // 0..15
    const int b    = blockIdx.y;          // 0..255
    const int tid  = threadIdx.x;
    const int lane = tid & 63;
    const int wv   = tid >> 6;
    const int s    = wv & 1;              // col span
    const int q    = wv >> 1;             // row strip
    const int ow   = 62 * s + lane;
    const int owc  = min(ow, 123);
    const int owc2 = 2 * owc;
    const int ihlo = 16 * t - 1;

    const int sr  = __builtin_amdgcn_readfirstlane(tid >> 7); // wave-uniform
    const int sm  = tid & 127;            // float2 index
    const int smc = min(sm, 124);

    float acc[5][6];
#pragma unroll
    for (int j = 0; j < 5; ++j)
#pragma unroll
        for (int oc = 0; oc < 6; ++oc) acc[j][oc] = 0.f;

    const float* xb = x + (size_t)b * 3 * 62500;
    const bool interior = (t >= 1) && (t <= 14);   // all 21 rows in-bounds

    if (tid < 22) { xs[0][tid][0] = 0.f; xs[1][tid][0] = 0.f; }  // col -1 pad

    // compute one ci from buffer xsb: load 13 row windows, then kh-outer FMAs
    auto compute = [&](int ci, const float (*xsb)[258]) {
        float rr[13][5];
#pragma unroll
        for (int r = 0; r < 13; ++r) {
            const float* pp = &xsb[8 * q + r][owc2];
            rr[r][0] = pp[0]; rr[r][1] = pp[1]; rr[r][2] = pp[2];
            rr[r][3] = pp[3]; rr[r][4] = pp[4];
        }
        return [=, &acc](const float* wbase) {
            (void)wbase;
        };
    };
    (void)compute;  // (lambda trick unused; straight code below)

    if (interior) {
        // prologue: DMA ci=0 -> buf0 (4 instrs/row, wave-partitioned rows;
        // k=3 spills cols 250..255 -> next input row, in-bounds interior,
        // lands in sink cols 251..257)
        {
            const float* xc = xb;
            for (int r = wv; r < 21; r += 4) {
                const float* src = xc + (size_t)(ihlo + r) * 250 + lane;
#pragma unroll
                for (int k = 0; k < 4; ++k)
                    gload_lds4(src + 64 * k, &xs[0][r][1 + 64 * k]);
            }
        }
#pragma unroll 1
        for (int ci = 0; ci < 3; ++ci) {
            const int cur = ci & 1;
            __syncthreads();              // drains DMA(ci) -> buf[cur] ready
            const float(*xsb)[258] = xs[cur];
            // all of this iteration's LDS reads FIRST...
            float rr[13][5];
#pragma unroll
            for (int r = 0; r < 13; ++r) {
                const float* pp = &xsb[8 * q + r][owc2];
                rr[r][0] = pp[0]; rr[r][1] = pp[1]; rr[r][2] = pp[2];
                rr[r][3] = pp[3]; rr[r][4] = pp[4];
            }
            // ...then issue DMA(ci+1) into the other buffer (completes under
            // the FMA block; drained at the next barrier)
            if (ci < 2) {
                const float* xc = xb + (size_t)(ci + 1) * 62500;
                for (int r = wv; r < 21; r += 4) {
                    const float* src = xc + (size_t)(ihlo + r) * 250 + lane;
#pragma unroll
                    for (int k = 0; k < 4; ++k)
                        gload_lds4(src + 64 * k, &xs[cur ^ 1][r][1 + 64 * k]);
                }
            }
#pragma unroll
            for (int kh = 0; kh < 5; ++kh) {
                float wk[6][5];
#pragma unroll
                for (int oc = 0; oc < 6; ++oc)
#pragma unroll
                    for (int kw = 0; kw < 5; ++kw)
                        wk[oc][kw] = w[((oc * 3 + ci) * 5 + kh) * 5 + kw];
#pragma unroll
                for (int j = 0; j < 5; ++j) {
                    const float* rp = rr[2 * j + kh];
#pragma unroll
                    for (int oc = 0; oc < 6; ++oc) {
                        float a = acc[j][oc];
                        a = fmaf(rp[0], wk[oc][0], a);
                        a = fmaf(rp[1], wk[oc][1], a);
                        a = fmaf(rp[2], wk[oc][2], a);
                        a = fmaf(rp[3], wk[oc][3], a);
                        a = fmaf(rp[4], wk[oc][4], a);
                        acc[j][oc] = a;
                    }
                }
            }
        }
    } else {
        // edge blocks: serial clamped staging into buf0 (proven path)
#pragma unroll 1
        for (int ci = 0; ci < 3; ++ci) {
            __syncthreads();
            const float* xc = xb + (size_t)ci * 62500;
            float2 vv[11];
#pragma unroll
            for (int i = 0; i < 11; ++i) {
                int r   = 2 * i + sr;                 // scalar
                int ih  = ihlo + r;                   // scalar
                int ihc = min(max(ih, 0), 249);       // scalar clamp
                bool ok = (ih >= 0) && (ih < 250);    // scalar
                float2 raw = *(const float2*)(xc + (size_t)ihc * 250 + (smc << 1));
                vv[i].x = ok ? raw.x : 0.f;
                vv[i].y = ok ? raw.y : 0.f;
            }
#pragma unroll
            for (int i = 0; i < 11; ++i) {
                int r = 2 * i + sr;                   // r=21 -> sink row
                xs[0][r][2 * sm + 1] = vv[i].x;
                xs[0][r][2 * sm + 2] = vv[i].y;
            }
            __syncthreads();
            float rr[13][5];
#pragma unroll
            for (int r = 0; r < 13; ++r) {
                const float* pp = &xs[0][8 * q + r][owc2];
                rr[r][0] = pp[0]; rr[r][1] = pp[1]; rr[r][2] = pp[2];
                rr[r][3] = pp[3]; rr[r][4] = pp[4];
            }
#pragma unroll
            for (int kh = 0; kh < 5; ++kh) {
                float wk[6][5];
#pragma unroll
                for (int oc = 0; oc < 6; ++oc)
#pragma unroll
                    for (int kw = 0; kw < 5; ++kw)
                        wk[oc][kw] = w[((oc * 3 + ci) * 5 + kh) * 5 + kw];
#pragma unroll
                for (int j = 0; j < 5; ++j) {
                    const float* rp = rr[2 * j + kh];
#pragma unroll
                    for (int oc = 0; oc < 6; ++oc) {
                        float a = acc[j][oc];
                        a = fmaf(rp[0], wk[oc][0], a);
                        a = fmaf(rp[1], wk[oc][1], a);
                        a = fmaf(rp[2], wk[oc][2], a);
                        a = fmaf(rp[3], wk[oc][3], a);
                        a = fmaf(rp[4], wk[oc][4], a);
                        acc[j][oc] = a;
                    }
                }
            }
        }
    }

    // epilogue: bias+relu, vertical max, horizontal max via shuffle, store
    const int pw   = ow;
    const int oh0  = 8 * t + 4 * q;
    const bool cok = (lane < 63) && (pw < 123);
#pragma unroll
    for (int oc = 0; oc < 6; ++oc) {
        float bv = bias[oc];
        float r0 = fmaxf(acc[0][oc] + bv, 0.f);
        float r1 = fmaxf(acc[1][oc] + bv, 0.f);
        float r2 = fmaxf(acc[2][oc] + bv, 0.f);
        float r3 = fmaxf(acc[3][oc] + bv, 0.f);
        float r4 = fmaxf(acc[4][oc] + bv, 0.f);
        float vm0 = fmaxf(r0, r1), vm1 = fmaxf(r1, r2);
        float vm2 = fmaxf(r2, r3), vm3 = fmaxf(r3, r4);
        float p0 = fmaxf(vm0, __shfl_down(vm0, 1));
        float p1v = fmaxf(vm1, __shfl_down(vm1, 1));
        float p2v = fmaxf(vm2, __shfl_down(vm2, 1));
        float p3 = fmaxf(vm3, __shfl_down(vm3, 1));
        if (cok) {
            float* op = p1 + (((size_t)b * 6 + oc) * 123) * 123 + pw;
            if (oh0 + 0 < 123) op[(size_t)(oh0 + 0) * 123] = p0;
            if (oh0 + 1 < 123) op[(size_t)(oh0 + 1) * 123] = p1v;
            if (oh0 + 2 < 123) op[(size_t)(oh0 + 2) * 123] = p2v;
            if (oh0 + 3 < 123) op[(size_t)(oh0 + 3) * 123] = p3;
        }
    }
}

// conv2+pool2. Block: image b, 8 pooled rows (v=blockIdx.x).
// 4 waves = 4 row strips; lane = conv col. Double-buffered DMA pipeline for
// interior blocks; col 124 becomes garbage under DMA so the g=123 zero-pad
// is applied in registers (ow==61 -> rr[c][2]=0; also correct for edge).
__global__ __launch_bounds__(256, 3) void k_c2p2(const float* __restrict__ p1,
                                                 const float* __restrict__ w,
                                                 const float* __restrict__ bias,
                                                 float* __restrict__ p2) {
    __shared__ float xs[2][20][130];

    const int v    = blockIdx.x;          // 0..7
    const int b    = blockIdx.y;
    const int tid  = threadIdx.x;
    const int lane = tid & 63;
    const int q    = tid >> 6;            // 0..3 (wave id)
    const int ow   = lane;
    const int owc  = min(ow, 61);
    const int owc2 = 2 * owc;
    const int ihlo = 16 * v - 1;

    const int sr   = __builtin_amdgcn_readfirstlane(tid >> 7); // wave-uniform
    const int sc   = tid & 127;           // 0..127
    const int scc  = min(sc, 122);
    const int wcol = (sc < 123) ? (sc + 1) : 129;   // sink col for edge lanes

    float acc[3][15];
#pragma unroll
    for (int j = 0; j < 3; ++j)
#pragma unroll
        for (int oc = 0; oc < 15; ++oc) acc[j][oc] = 0.f;

    const float* ib = p1 + (size_t)b * 6 * 15129;
    const bool interior = (v >= 1) && (v <= 6);   // all 19 rows in-bounds

    if (tid < 20) {
        xs[0][tid][0] = 0.f;   xs[1][tid][0] = 0.f;     // left pad
        xs[0][tid][124] = 0.f; xs[1][tid][124] = 0.f;   // right pad (edge)
    }

    if (interior) {
        // prologue: DMA ci=0 -> buf0 (2 instrs/row; k=1 spill in-bounds)
        {
            const float* xc = ib;
            for (int r = q; r < 19; r += 4) {
                const float* src = xc + (size_t)(ihlo + r) * 123 + lane;
                gload_lds4(src,      &xs[0][r][1]);
                gload_lds4(src + 64, &xs[0][r][65]);
            }
        }
#pragma unroll 1
        for (int ci = 0; ci < 6; ++ci) {
            const int cur = ci & 1;
            __syncthreads();              // drains DMA(ci)
            const float(*xsb)[130] = xs[cur];
            float rr[7][3];
#pragma unroll
            for (int c = 0; c < 7; ++c) {
                const float* pp = &xsb[4 * q + c][owc2];
                rr[c][0] = pp[0]; rr[c][1] = pp[1]; rr[c][2] = pp[2];
                if (ow == 61) rr[c][2] = 0.f;   // g=123 zero pad (reg-side)
            }
            if (ci < 5) {
                const float* xc = ib + (size_t)(ci + 1) * 15129;
                for (int r = q; r < 19; r += 4) {
                    const float* src = xc + (size_t)(ihlo + r) * 123 + lane;
                    gload_lds4(src,      &xs[cur ^ 1][r][1]);
                    gload_lds4(src + 64, &xs[cur ^ 1][r][65]);
                }
            }
#pragma unroll
            for (int kh = 0; kh < 3; ++kh) {
                float wk[15][3];
#pragma unroll
                for (int oc = 0; oc < 15; ++oc)
#pragma unroll
                    for (int kw = 0; kw < 3; ++kw)
                        wk[oc][kw] = w[((oc * 6 + ci) * 3 + kh) * 3 + kw];
#pragma unroll
                for (int j = 0; j < 3; ++j) {
                    const float* rp = rr[2 * j + kh];
#pragma unroll
                    for (int oc = 0; oc < 15; ++oc) {
                        float a = acc[j][oc];
                        a = fmaf(rp[0], wk[oc][0], a);
                        a = fmaf(rp[1], wk[oc][1], a);
                        a = fmaf(rp[2], wk[oc][2], a);
                        acc[j][oc] = a;
                    }
                }
            }
        }
    } else {
#pragma unroll 1
        for (int ci = 0; ci < 6; ++ci) {
            __syncthreads();
            const float* xc = ib + (size_t)ci * 15129;
            float vv[10];
#pragma unroll
            for (int i = 0; i < 10; ++i) {
                int r   = 2 * i + sr;                 // scalar
                int ih  = ihlo + r;                   // scalar
                int ihc = min(max(ih, 0), 122);       // scalar clamp
                bool ok = (ih >= 0) && (ih < 123);    // scalar
                float raw = xc[(size_t)ihc * 123 + scc];
                vv[i] = ok ? raw : 0.f;
            }
#pragma unroll
            for (int i = 0; i < 10; ++i) {
                int r = 2 * i + sr;                   // r=19 -> sink row
                xs[0][r][wcol] = vv[i];
            }
            __syncthreads();
            float rr[7][3];
#pragma unroll
            for (int c = 0; c < 7; ++c) {
                const float* pp = &xs[0][4 * q + c][owc2];
                rr[c][0] = pp[0]; rr[c][1] = pp[1]; rr[c][2] = pp[2];
                if (ow == 61) rr[c][2] = 0.f;   // already 0 in LDS; uniform
            }
#pragma unroll
            for (int kh = 0; kh < 3; ++kh) {
                float wk[15][3];
#pragma unroll
                for (int oc = 0; oc < 15; ++oc)
#pragma unroll
                    for (int kw = 0; kw < 3; ++kw)
                        wk[oc][kw] = w[((oc * 6 + ci) * 3 + kh) * 3 + kw];
#pragma unroll
                for (int j = 0; j < 3; ++j) {
                    const float* rp = rr[2 * j + kh];
#pragma unroll
                    for (int oc = 0; oc < 15; ++oc) {
                        float a = acc[j][oc];
                        a = fmaf(rp[0], wk[oc][0], a);
                        a = fmaf(rp[1], wk[oc][1], a);
                        a = fmaf(rp[2], wk[oc][2], a);
                        acc[j][oc] = a;
                    }
                }
            }
        }
    }

    const int pw   = ow;
    const int oh0  = 8 * v + 2 * q;
    const bool cok = (lane < 61);
#pragma unroll
    for (int oc = 0; oc < 15; ++oc) {
        float bv = bias[oc];
        float r0 = fmaxf(acc[0][oc] + bv, 0.f);
        float r1 = fmaxf(acc[1][oc] + bv, 0.f);
        float r2 = fmaxf(acc[2][oc] + bv, 0.f);
        float vm0 = fmaxf(r0, r1), vm1 = fmaxf(r1, r2);
        float p0 = fmaxf(vm0, __shfl_down(vm0, 1));
        float p1v = fmaxf(vm1, __shfl_down(vm1, 1));
        if (cok) {
            float* op = p2 + (((size_t)b * 15 + oc) * 61) * 61 + pw;
            if (oh0 + 0 < 61) op[(size_t)(oh0 + 0) * 61] = p0;
            if (oh0 + 1 < 61) op[(size_t)(oh0 + 1) * 61] = p1v;
        }
    }
}

// fc1 split-K GEMM: A=p2[256][55815], B=fc1_w[120][55815].
// grid (256 kb, 2 mt), BK=64, batched staging, b128 LDS fragments.
// LDS XOR-swizzle: float4 slot ^= (row&7); kills the 4-way (A) / 16-way (B)
// read conflicts of the unswizzled [128][64] layout. (round-10 version)
__global__ __launch_bounds__(256) void k_fc1(const float* __restrict__ A,
                                             const float* __restrict__ B,
                                             float* __restrict__ partial) {
    __shared__ float As[128][64];
    __shared__ float Bs[128][64];
    const int K = 55815;
    int tid = threadIdx.x;
    int kb  = blockIdx.x;          // 0..255
    int m0  = blockIdx.y * 128;
    int mx  = tid >> 4;            // 0..15
    int nx  = tid & 15;            // 0..15
    int kl  = tid & 63;            // staging col
    int mb  = tid >> 6;            // staging row base

    // zero-fill B rows 120..127 (whole rows -> swizzle-invariant)
    Bs[120 + mb][kl] = 0.f;
    Bs[124 + mb][kl] = 0.f;

    float acc[8][8];
#pragma unroll
    for (int i = 0; i < 8; ++i)
#pragma unroll
        for (int j = 0; j < 8; ++j) acc[i][j] = 0.f;

    for (int ch = kb; ch < 873; ch += 256) {   // 873 = ceil(55815/64)
        int k    = ch * 64 + kl;
        bool kok = (k < K);
        int kc   = kok ? k : K - 1;
        __syncthreads();
#pragma unroll
        for (int batch = 0; batch < 4; ++batch) {
            float va[8], vb[8];
#pragma unroll
            for (int u = 0; u < 8; ++u) {
                int m = mb + 4 * (batch * 8 + u);
                va[u] = A[(size_t)(m0 + m) * K + kc];
            }
#pragma unroll
            for (int u = 0; u < 8; ++u) {
                if (batch < 3 || u < 6) {      // B rows 0..119 only
                    int m = mb + 4 * (batch * 8 + u);
                    vb[u] = B[(size_t)m * K + kc];
                }
            }
#pragma unroll
            for (int u = 0; u < 8; ++u) {
                int m = mb + 4 * (batch * 8 + u);
                As[m][kl ^ ((m & 7) << 2)] = kok ? va[u] : 0.f;
            }
#pragma unroll
            for (int u = 0; u < 8; ++u) {
                if (batch < 3 || u < 6) {
                    int m = mb + 4 * (batch * 8 + u);
                    Bs[m][kl ^ ((m & 7) << 2)] = kok ? vb[u] : 0.f;
                }
            }
        }
        __syncthreads();
#pragma unroll 2
        for (int k4 = 0; k4 < 16; ++k4) {
            float4 af[8], bf[8];
#pragma unroll
            for (int i = 0; i < 8; ++i) {
                int m = mx + 16 * i;
                af[i] = *(const float4*)&As[m][(k4 * 4) ^ ((m & 7) << 2)];
            }
#pragma unroll
            for (int j = 0; j < 8; ++j) {
                int n = nx + 16 * j;
                bf[j] = *(const float4*)&Bs[n][(k4 * 4) ^ ((n & 7) << 2)];
            }
#pragma unroll
            for (int i = 0; i < 8; ++i)
#pragma unroll
                for (int j = 0; j < 8; ++j) {
                    acc[i][j] = fmaf(af[i].x, bf[j].x, acc[i][j]);
                    acc[i][j] = fmaf(af[i].y, bf[j].y, acc[i][j]);
                    acc[i][j] = fmaf(af[i].z, bf[j].z, acc[i][j]);
                    acc[i][j] = fmaf(af[i].w, bf[j].w, acc[i][j]);
                }
        }
    }

    float* pp = partial + (size_t)kb * 30720;
#pragma unroll
    for (int i = 0; i < 8; ++i) {
        int m = m0 + mx + 16 * i;
#pragma unroll
        for (int j = 0; j < 8; ++j) {
            int n = nx + 16 * j;
            if (n < 120) pp[m * 120 + n] = acc[i][j];
        }
    }
}

// reduce stage 1: block (g, s) sums partials kb = 32s..32s+31 for its 256 idx
__global__ __launch_bounds__(256) void k_fc1red1(const float* __restrict__ partial,
                                                 float* __restrict__ partial2) {
    int idx = blockIdx.x * 256 + threadIdx.x;   // 0..30719
    int s   = blockIdx.y;                       // 0..7
    const float* p = partial + (size_t)(s * 32) * 30720 + idx;
    float acc = 0.f;
#pragma unroll 8
    for (int kb = 0; kb < 32; ++kb) acc += p[(size_t)kb * 30720];
    partial2[(size_t)s * 30720 + idx] = acc;
}

// reduce stage 2: 8-way + bias + relu -> fc1out[256][120]
__global__ __launch_bounds__(256) void k_fc1red2(const float* __restrict__ partial2,
                                                 const float* __restrict__ bias,
                                                 float* __restrict__ out) {
    int idx = blockIdx.x * 256 + threadIdx.x;   // 30720
    int n = idx % 120;
    float s = bias[n];
#pragma unroll
    for (int k = 0; k < 8; ++k) s += partial2[(size_t)k * 30720 + idx];
    out[idx] = fmaxf(s, 0.f);
}

// fc2: features[256][84] = fc1out[256][120] @ w[84][120]^T + b
__global__ __launch_bounds__(256) void k_fc2(const float* __restrict__ h,
                                             const float* __restrict__ w,
                                             const float* __restrict__ bias,
                                             float* __restrict__ out) {
    int idx = blockIdx.x * 256 + threadIdx.x;   // 21504
    int n = idx % 84;
    int m = idx / 84;
    const float* hp = h + m * 120;
    const float* wp = w + n * 120;
    float s = bias[n];
#pragma unroll 4
    for (int k = 0; k < 120; ++k) s = fmaf(hp[k], wp[k], s);
    out[idx] = s;
}

// head: fc3 -> tanh-param layer -> sigmoid; also row norms of features
__global__ __launch_bounds__(256) void k_head(const float* __restrict__ f,
                                              const float* __restrict__ w3,
                                              const float* __restrict__ b3,
                                              const float* __restrict__ plw,
                                              const float* __restrict__ plb,
                                              const float* __restrict__ pls,
                                              const float* __restrict__ plbias,
                                              float* __restrict__ probs,
                                              float* __restrict__ norms) {
    int b = threadIdx.x;            // 0..255, single block
    const float* fp = f + b * 84;
    float nsq = 0.f, lg = b3[0];
#pragma unroll 4
    for (int k = 0; k < 84; ++k) {
        float v = fp[k];
        nsq = fmaf(v, v, nsq);
        lg  = fmaf(v, w3[k], lg);
    }
    float z = tanhf(lg * plw[0] + plb[0]) * pls[0] + plbias[0];
    probs[b] = 1.f / (1.f + expf(-z));
    norms[b] = sqrtf(nsq);
}

// graph: block i computes cosine-sim row i, adjacency, degree-weighted agg
__global__ __launch_bounds__(256) void k_graph(const float* __restrict__ f,
                                               const float* __restrict__ probs,
                                               const float* __restrict__ norms,
                                               float* __restrict__ out) {
    __shared__ float fi[84];
    __shared__ float sd[4], sv[4];
    int i = blockIdx.x;
    int j = threadIdx.x;
    if (j < 84) fi[j] = f[i * 84 + j];
    __syncthreads();
    const float* fj = f + j * 84;
    float dot = 0.f;
#pragma unroll 4
    for (int k = 0; k < 84; ++k) dot = fmaf(fi[k], fj[k], dot);
    float sim = dot / (norms[i] * norms[j] + 1e-12f);
    bool adj = (j != i) && (sim >= 0.0f);
    float d = adj ? 1.f : 0.f;
    float v = adj ? probs[j] : 0.f;
#pragma unroll
    for (int off = 32; off >= 1; off >>= 1) {
        d += __shfl_down(d, off);
        v += __shfl_down(v, off);
    }
    int wave = j >> 6, lane = j & 63;
    if (lane == 0) { sd[wave] = d; sv[wave] = v; }
    __syncthreads();
    if (j == 0) {
        float D = sd[0] + sd[1] + sd[2] + sd[3];
        float V = sv[0] + sv[1] + sv[2] + sv[3];
        float nm = (D > 0.f) ? (V / fmaxf(D, 1.f)) : 0.f;
        float agg = (probs[i] + nm) / (1.f + D);
        out[2 * i]     = agg;
        out[2 * i + 1] = 1.f - agg;
    }
}

extern "C" void kernel_launch(void* const* d_in, const int* in_sizes, int n_in,
                              void* d_out, int out_size, void* d_ws, size_t ws_size,
                              hipStream_t stream) {
    const float* x    = (const float*)d_in[0];
    const float* w1   = (const float*)d_in[1];
    const float* b1   = (const float*)d_in[2];
    const float* w2   = (const float*)d_in[3];
    const float* b2   = (const float*)d_in[4];
    const float* fw1  = (const float*)d_in[5];
    const float* fb1  = (const float*)d_in[6];
    const float* fw2  = (const float*)d_in[7];
    const float* fb2  = (const float*)d_in[8];
    const float* fw3  = (const float*)d_in[9];
    const float* fb3  = (const float*)d_in[10];
    const float* plw  = (const float*)d_in[11];
    const float* plb  = (const float*)d_in[12];
    const float* pls  = (const float*)d_in[13];
    const float* plbi = (const float*)d_in[14];
    float* out = (float*)d_out;

    float* ws = (float*)d_ws;
    float* p1       = ws;                          // 23,238,144 f
    float* p2       = p1 + 23238144;               // 14,288,640 f
    float* partial  = p2 + 14288640;               // 7,864,320 f
    float* fc1out   = partial + 7864320;           // 30,720 f
    float* features = fc1out + 30720;              // 21,504 f
    float* probs    = features + 21504;            // 256 f
    float* norms    = probs + 256;                 // 256 f
    float* partial2 = norms + 256;                 // 245,760 f

    k_c1p1<<<dim3(16, 256), 256, 0, stream>>>(x, w1, b1, p1);
    k_c2p2<<<dim3(8, 256), 256, 0, stream>>>(p1, w2, b2, p2);
    k_fc1<<<dim3(256, 2), 256, 0, stream>>>(p2, fw1, partial);
    k_fc1red1<<<dim3(120, 8), 256, 0, stream>>>(partial, partial2);
    k_fc1red2<<<120, 256, 0, stream>>>(partial2, fb1, fc1out);
    k_fc2<<<84, 256, 0, stream>>>(fc1out, fw2, fb2, features);
    k_head<<<1, 256, 0, stream>>>(features, fw3, fb3, plw, plb, pls, plbi,
                                  probs, norms);
    k_graph<<<256, 256, 0, stream>>>(features, probs, norms, out);
}